// Round 2
// baseline (1483.675 us; speedup 1.0000x reference)
//
#include <hip/hip_runtime.h>
#include <stdint.h>

typedef unsigned short u16;
typedef __attribute__((ext_vector_type(8))) __bf16 bf16x8;
typedef __attribute__((ext_vector_type(8))) short short8;
typedef __attribute__((ext_vector_type(4))) float f32x4;

#define D_DIM 4096
#define M_TOK 8192

// ---- GEMM geometry: 256x256 tile, 8 waves, K-slices of 32, ring-4 LDS ----
#define BM 256
#define BN 256
#define BKS 32
#define SLICE_U16 (BM * BKS)  // 8192 u16 = 16 KB per matrix per slice

// exact round-to-nearest-even fp32 -> bf16 (inputs finite)
__device__ __forceinline__ u16 f2bf(float f) {
  unsigned u = __builtin_bit_cast(unsigned, f);
  u += 0x7fffu + ((u >> 16) & 1u);
  return (u16)(u >> 16);
}
__device__ __forceinline__ float bf2f(u16 b) {
  unsigned u = ((unsigned)b) << 16;
  return __builtin_bit_cast(float, u);
}

// direct global->LDS DMA, 16B per lane; LDS dest is wave-uniform base + lane*16
#define LOAD_LDS16(gp, lp)                                                     \
  __builtin_amdgcn_global_load_lds(                                            \
      (const __attribute__((address_space(1))) void*)((const void*)(gp)),      \
      (__attribute__((address_space(3))) void*)((void*)(lp)), 16, 0, 0)

// ---------------- abs-mean (two-pass, deterministic) ----------------
__global__ void abs_partial_k(const float* __restrict__ w, float* __restrict__ partial) {
  const int n4 = (D_DIM * D_DIM) / 4;
  float s = 0.f;
  for (int i = blockIdx.x * 256 + threadIdx.x; i < n4; i += 1024 * 256) {
    float4 v = ((const float4*)w)[i];
    s += fabsf(v.x) + fabsf(v.y) + fabsf(v.z) + fabsf(v.w);
  }
#pragma unroll
  for (int o = 32; o > 0; o >>= 1) s += __shfl_down(s, o, 64);
  __shared__ float sm[4];
  if ((threadIdx.x & 63) == 0) sm[threadIdx.x >> 6] = s;
  __syncthreads();
  if (threadIdx.x == 0) partial[blockIdx.x] = sm[0] + sm[1] + sm[2] + sm[3];
}

__global__ void finalize_scale_k(const float* __restrict__ partial, float* __restrict__ scale) {
  float s = 0.f;
  for (int i = threadIdx.x; i < 1024; i += 256) s += partial[i];
#pragma unroll
  for (int o = 32; o > 0; o >>= 1) s += __shfl_down(s, o, 64);
  __shared__ float sm[4];
  if ((threadIdx.x & 63) == 0) sm[threadIdx.x >> 6] = s;
  __syncthreads();
  if (threadIdx.x == 0)
    scale[0] = (sm[0] + sm[1] + sm[2] + sm[3]) * (1.0f / 16777216.0f) + 1e-8f;
}

// ---------------- ternarize: clip(round(w/scale),-1,1) -> bf16 ----------------
__global__ void ternarize_k(const float* __restrict__ w, u16* __restrict__ t,
                            const float* __restrict__ scale) {
  const float sc = scale[0];
  int i = blockIdx.x * 256 + threadIdx.x;  // grid covers n/4 exactly
  float4 v = ((const float4*)w)[i];
  ushort4 o;
  o.x = f2bf(fminf(fmaxf(rintf(v.x / sc), -1.f), 1.f));
  o.y = f2bf(fminf(fmaxf(rintf(v.y / sc), -1.f), 1.f));
  o.z = f2bf(fminf(fmaxf(rintf(v.z / sc), -1.f), 1.f));
  o.w = f2bf(fminf(fmaxf(rintf(v.w / sc), -1.f), 1.f));
  ((ushort4*)t)[i] = o;
}

// ---------------- fused RMSNorm + SiLU -> bf16 ----------------
__global__ void rms_silu_f32_k(const float* __restrict__ x, u16* __restrict__ h) {
  const int row = blockIdx.x;
  const float4* xr = (const float4*)(x + (size_t)row * D_DIM);
  float4 v[4];
  float ss = 0.f;
#pragma unroll
  for (int i = 0; i < 4; ++i) {
    v[i] = xr[threadIdx.x + i * 256];
    ss += v[i].x * v[i].x + v[i].y * v[i].y + v[i].z * v[i].z + v[i].w * v[i].w;
  }
#pragma unroll
  for (int o = 32; o > 0; o >>= 1) ss += __shfl_down(ss, o, 64);
  __shared__ float sm[4];
  if ((threadIdx.x & 63) == 0) sm[threadIdx.x >> 6] = ss;
  __syncthreads();
  const float ms = (sm[0] + sm[1] + sm[2] + sm[3]) * (1.0f / (float)D_DIM);
  const float r = rsqrtf(ms + 1.1920929e-7f);  // eps = finfo(f32).eps
  ushort4* hr = (ushort4*)(h + (size_t)row * D_DIM);
#pragma unroll
  for (int i = 0; i < 4; ++i) {
    float z0 = v[i].x * r, z1 = v[i].y * r, z2 = v[i].z * r, z3 = v[i].w * r;
    ushort4 o;
    o.x = f2bf(z0 / (1.f + __expf(-z0)));
    o.y = f2bf(z1 / (1.f + __expf(-z1)));
    o.z = f2bf(z2 / (1.f + __expf(-z2)));
    o.w = f2bf(z3 / (1.f + __expf(-z3)));
    hr[threadIdx.x + i * 256] = o;
  }
}

__global__ void rms_silu_bf16_k(const u16* __restrict__ x, u16* __restrict__ h) {
  const int row = blockIdx.x;
  const ushort4* xr = (const ushort4*)(x + (size_t)row * D_DIM);
  float4 v[4];
  float ss = 0.f;
#pragma unroll
  for (int i = 0; i < 4; ++i) {
    ushort4 b = xr[threadIdx.x + i * 256];
    v[i] = make_float4(bf2f(b.x), bf2f(b.y), bf2f(b.z), bf2f(b.w));
    ss += v[i].x * v[i].x + v[i].y * v[i].y + v[i].z * v[i].z + v[i].w * v[i].w;
  }
#pragma unroll
  for (int o = 32; o > 0; o >>= 1) ss += __shfl_down(ss, o, 64);
  __shared__ float sm[4];
  if ((threadIdx.x & 63) == 0) sm[threadIdx.x >> 6] = ss;
  __syncthreads();
  const float ms = (sm[0] + sm[1] + sm[2] + sm[3]) * (1.0f / (float)D_DIM);
  const float r = rsqrtf(ms + 1.1920929e-7f);
  ushort4* hr = (ushort4*)(h + (size_t)row * D_DIM);
#pragma unroll
  for (int i = 0; i < 4; ++i) {
    float z0 = v[i].x * r, z1 = v[i].y * r, z2 = v[i].z * r, z3 = v[i].w * r;
    ushort4 o;
    o.x = f2bf(z0 / (1.f + __expf(-z0)));
    o.y = f2bf(z1 / (1.f + __expf(-z1)));
    o.z = f2bf(z2 / (1.f + __expf(-z2)));
    o.w = f2bf(z3 / (1.f + __expf(-z3)));
    hr[threadIdx.x + i * 256] = o;
  }
}

// ---------------- bf16 GEMM: C[M][N] = A[M][K] * B[N][K]^T ----------------
// 256x256 tile, 8 waves (2Mx4N), per-wave C = 128x64 (8x4 frags of 16x16).
// K pipelined in BK=32 slices through a ring of 4 LDS buffers (128 KiB):
//   iter s: issue global_load_lds for slice s+2 -> ds_read slice s -> 32 MFMA
//           -> s_waitcnt vmcnt(4); s_barrier      (counted vmcnt, never 0)
// Safety: vmcnt(4) before the barrier leaves only slice s+2's 4 loads/thread
// outstanding -> after the barrier slice s+1 has landed workgroup-wide.
// Ring[(s+2)&3] was last ds_read at slice s-2 (two barriers ago) -> WAR safe.
// LDS swizzle (conflict-free): read slot g = fq ^ ((fr>>2)&3); staging
// pre-swizzles the per-lane GLOBAL source (global_load_lds dest must stay
// linear), sg = (lane&3) ^ ((lane>>4)&3) -- the same involution.
// Register budget: acc 128 VGPR + frags ~20 (af streamed per-mi) -> ~175,
// safely under the 256 cap from __launch_bounds__(512,2); no spill, so the
// hand-counted vmcnt sees only the 4 global_load_lds ops per STAGE.
template <typename OUT>
__global__ __launch_bounds__(512, 2) void gemm_bt_k(
    const u16* __restrict__ A, const u16* __restrict__ B, OUT* __restrict__ C,
    int M, int N, int K) {
  __shared__ u16 As[4][SLICE_U16];  // 64 KB
  __shared__ u16 Bs[4][SLICE_U16];  // 64 KB

  const int tid = threadIdx.x;
  const int wave = tid >> 6;
  const int lane = tid & 63;

  // XCD-aware bijective swizzle (nwg % 8 == 0): each XCD gets a contiguous
  // chunk of 64 lids = 2 full B-panels (4 MB -> L2-resident per XCD).
  const int nwg = gridDim.x;
  const int cpx = nwg >> 3;
  const int bid = blockIdx.x;
  const int lid = (bid & 7) * cpx + (bid >> 3);
  const int tilesM = M >> 8;
  const int tm = lid % tilesM;
  const int tn = lid / tilesM;
  const int bm = tm * BM;
  const int bn = tn * BN;

  const int wr = wave >> 2;  // 0..1  (M)
  const int wc = wave & 3;   // 0..3  (N)
  const int wm = wr * 128;
  const int wn = wc * 64;

  // ---- fragment LDS read offsets (u16 units), swizzled granule ----
  const int fr = lane & 15;
  const int fq = lane >> 4;
  const int g = fq ^ ((fr >> 2) & 3);
  const int aoff = (wm + fr) * BKS + g * 8;
  const int boff = (wn + fr) * BKS + g * 8;

  // ---- staging: per wave 16 rows x 64B, 2 rounds (rows +0 / +128) each ----
  const int srow = lane >> 2;                      // row within wave's 16
  const int sg = (lane & 3) ^ ((lane >> 4) & 3);   // pre-swizzled src granule
  const size_t ldK = (size_t)K;
  const u16* agp = A + (size_t)(bm + wave * 16 + srow) * ldK + (size_t)(sg * 8);
  const u16* bgp = B + (size_t)(bn + wave * 16 + srow) * ldK + (size_t)(sg * 8);
  const int sdst = wave * 16 * BKS;  // wave-uniform LDS dest (u16)

  f32x4 acc[8][4];
#pragma unroll
  for (int i = 0; i < 8; ++i)
#pragma unroll
    for (int j = 0; j < 4; ++j) acc[i][j] = {0.f, 0.f, 0.f, 0.f};

#define STAGE(s, r)                                                            \
  do {                                                                         \
    const u16* a0 = agp + (size_t)(s)*BKS;                                     \
    const u16* b0 = bgp + (size_t)(s)*BKS;                                     \
    LOAD_LDS16(a0, &As[r][sdst]);                                              \
    LOAD_LDS16(a0 + (size_t)128 * ldK, &As[r][sdst + 128 * BKS]);              \
    LOAD_LDS16(b0, &Bs[r][sdst]);                                              \
    LOAD_LDS16(b0 + (size_t)128 * ldK, &Bs[r][sdst + 128 * BKS]);              \
  } while (0)

// B frags held live (16 VGPR); A frags streamed one at a time (4 VGPR):
// 1 ds_read_b128 -> 4 MFMA, m201's per-phase shape, minimal register load.
#define COMPUTE(r)                                                             \
  do {                                                                         \
    const u16* ab = &As[r][aoff];                                              \
    const u16* bb = &Bs[r][boff];                                              \
    bf16x8 bfv[4];                                                             \
    _Pragma("unroll") for (int ni = 0; ni < 4; ++ni) bfv[ni] =                 \
        __builtin_bit_cast(bf16x8, *(const short8*)(bb + ni * (16 * BKS)));    \
    __builtin_amdgcn_s_setprio(1);                                             \
    _Pragma("unroll") for (int mi = 0; mi < 8; ++mi) {                         \
      bf16x8 af =                                                              \
          __builtin_bit_cast(bf16x8, *(const short8*)(ab + mi * (16 * BKS))); \
      _Pragma("unroll") for (int ni = 0; ni < 4; ++ni) acc[mi][ni] =           \
          __builtin_amdgcn_mfma_f32_16x16x32_bf16(af, bfv[ni],                 \
                                                  acc[mi][ni], 0, 0, 0);       \
    }                                                                          \
    __builtin_amdgcn_s_setprio(0);                                             \
  } while (0)

  const int ns = K / BKS;  // 128
  STAGE(0, 0);
  STAGE(1, 1);
  asm volatile("s_waitcnt vmcnt(4)\n\ts_barrier" ::: "memory");  // slice 0 in
  for (int s = 0; s < ns - 2; ++s) {
    STAGE(s + 2, (s + 2) & 3);
    COMPUTE(s & 3);
    asm volatile("s_waitcnt vmcnt(4)\n\ts_barrier" ::: "memory");
  }
  COMPUTE((ns - 2) & 3);
  asm volatile("s_waitcnt vmcnt(0)\n\ts_barrier" ::: "memory");  // tail drain
  COMPUTE((ns - 1) & 3);
#undef STAGE
#undef COMPUTE

  // epilogue: C/D layout col=lane&15, row=(lane>>4)*4+reg (m89-verified)
  const int crow0 = bm + wm + (lane >> 4) * 4;
  const int ccol0 = bn + wn + (lane & 15);
#pragma unroll
  for (int mi = 0; mi < 8; ++mi)
#pragma unroll
    for (int ni = 0; ni < 4; ++ni)
#pragma unroll
      for (int r = 0; r < 4; ++r) {
        float v = acc[mi][ni][r];
        size_t idx = (size_t)(crow0 + mi * 16 + r) * N + (ccol0 + ni * 16);
        if constexpr (__is_same(OUT, float))
          C[idx] = v;
        else
          C[idx] = f2bf(v);
      }
}

// ---------------- driver ----------------
extern "C" void kernel_launch(void* const* d_in, const int* in_sizes, int n_in,
                              void* d_out, int out_size, void* d_ws, size_t ws_size,
                              hipStream_t stream) {
  const float* x = (const float*)d_in[0];
  const float* w[3] = {(const float*)d_in[1], (const float*)d_in[2], (const float*)d_in[3]};

  // ws layout (~160 MB): scale | partials | ternary bf16 (reused) | h bf16 | xmid bf16
  char* ws = (char*)d_ws;
  float* scale = (float*)ws;                               // 16 B
  float* partial = (float*)(ws + 256);                     // 4 KB
  u16* tW = (u16*)(ws + 8192);                             // 32 MB
  u16* h = (u16*)(ws + 8192 + 33554432);                   // 64 MB
  u16* xmid = (u16*)(ws + 8192 + 33554432 + 67108864);     // 64 MB

  dim3 grid((M_TOK / BM) * (D_DIM / BN));  // 512 wgs, 1D for XCD swizzle
  for (int l = 0; l < 3; ++l) {
    abs_partial_k<<<1024, 256, 0, stream>>>(w[l], partial);
    finalize_scale_k<<<1, 256, 0, stream>>>(partial, scale);
    ternarize_k<<<(D_DIM * D_DIM) / 4 / 256, 256, 0, stream>>>(w[l], tW, scale);
    if (l == 0)
      rms_silu_f32_k<<<M_TOK, 256, 0, stream>>>(x, h);
    else
      rms_silu_bf16_k<<<M_TOK, 256, 0, stream>>>(xmid, h);
    if (l == 2)
      gemm_bt_k<float><<<grid, 512, 0, stream>>>(h, tW, (float*)d_out, M_TOK, D_DIM, D_DIM);
    else
      gemm_bt_k<u16><<<grid, 512, 0, stream>>>(h, tW, xmid, M_TOK, D_DIM, D_DIM);
  }
}

// Round 3
// 1462.999 us; speedup vs baseline: 1.0141x; 1.0141x over previous
//
#include <hip/hip_runtime.h>
#include <stdint.h>

typedef unsigned short u16;
typedef __attribute__((ext_vector_type(8))) __bf16 bf16x8;
typedef __attribute__((ext_vector_type(8))) short short8;
typedef __attribute__((ext_vector_type(4))) float f32x4;

#define D_DIM 4096
#define M_TOK 8192

// ---- GEMM geometry: 256x256 tile, 8 waves, K-slices of 32, ring-4 LDS ----
#define BM 256
#define BN 256
#define BKS 32
#define SLICE_U16 (BM * BKS)  // 8192 u16 = 16 KB per matrix per slice

// exact round-to-nearest-even fp32 -> bf16 (inputs finite)
__device__ __forceinline__ u16 f2bf(float f) {
  unsigned u = __builtin_bit_cast(unsigned, f);
  u += 0x7fffu + ((u >> 16) & 1u);
  return (u16)(u >> 16);
}
__device__ __forceinline__ float bf2f(u16 b) {
  unsigned u = ((unsigned)b) << 16;
  return __builtin_bit_cast(float, u);
}

// direct global->LDS DMA, 16B per lane; LDS dest is wave-uniform base + lane*16
#define LOAD_LDS16(gp, lp)                                                     \
  __builtin_amdgcn_global_load_lds(                                            \
      (const __attribute__((address_space(1))) void*)((const void*)(gp)),      \
      (__attribute__((address_space(3))) void*)((void*)(lp)), 16, 0, 0)

// ---------------- abs-mean (two-pass, deterministic) ----------------
__global__ void abs_partial_k(const float* __restrict__ w, float* __restrict__ partial) {
  const int n4 = (D_DIM * D_DIM) / 4;
  float s = 0.f;
  for (int i = blockIdx.x * 256 + threadIdx.x; i < n4; i += 1024 * 256) {
    float4 v = ((const float4*)w)[i];
    s += fabsf(v.x) + fabsf(v.y) + fabsf(v.z) + fabsf(v.w);
  }
#pragma unroll
  for (int o = 32; o > 0; o >>= 1) s += __shfl_down(s, o, 64);
  __shared__ float sm[4];
  if ((threadIdx.x & 63) == 0) sm[threadIdx.x >> 6] = s;
  __syncthreads();
  if (threadIdx.x == 0) partial[blockIdx.x] = sm[0] + sm[1] + sm[2] + sm[3];
}

__global__ void finalize_scale_k(const float* __restrict__ partial, float* __restrict__ scale) {
  float s = 0.f;
  for (int i = threadIdx.x; i < 1024; i += 256) s += partial[i];
#pragma unroll
  for (int o = 32; o > 0; o >>= 1) s += __shfl_down(s, o, 64);
  __shared__ float sm[4];
  if ((threadIdx.x & 63) == 0) sm[threadIdx.x >> 6] = s;
  __syncthreads();
  if (threadIdx.x == 0)
    scale[0] = (sm[0] + sm[1] + sm[2] + sm[3]) * (1.0f / 16777216.0f) + 1e-8f;
}

// ---------------- ternarize: clip(round(w/scale),-1,1) -> bf16 ----------------
__global__ void ternarize_k(const float* __restrict__ w, u16* __restrict__ t,
                            const float* __restrict__ scale) {
  const float sc = scale[0];
  int i = blockIdx.x * 256 + threadIdx.x;  // grid covers n/4 exactly
  float4 v = ((const float4*)w)[i];
  ushort4 o;
  o.x = f2bf(fminf(fmaxf(rintf(v.x / sc), -1.f), 1.f));
  o.y = f2bf(fminf(fmaxf(rintf(v.y / sc), -1.f), 1.f));
  o.z = f2bf(fminf(fmaxf(rintf(v.z / sc), -1.f), 1.f));
  o.w = f2bf(fminf(fmaxf(rintf(v.w / sc), -1.f), 1.f));
  ((ushort4*)t)[i] = o;
}

// ---------------- fused RMSNorm + SiLU -> bf16 ----------------
__global__ void rms_silu_f32_k(const float* __restrict__ x, u16* __restrict__ h) {
  const int row = blockIdx.x;
  const float4* xr = (const float4*)(x + (size_t)row * D_DIM);
  float4 v[4];
  float ss = 0.f;
#pragma unroll
  for (int i = 0; i < 4; ++i) {
    v[i] = xr[threadIdx.x + i * 256];
    ss += v[i].x * v[i].x + v[i].y * v[i].y + v[i].z * v[i].z + v[i].w * v[i].w;
  }
#pragma unroll
  for (int o = 32; o > 0; o >>= 1) ss += __shfl_down(ss, o, 64);
  __shared__ float sm[4];
  if ((threadIdx.x & 63) == 0) sm[threadIdx.x >> 6] = ss;
  __syncthreads();
  const float ms = (sm[0] + sm[1] + sm[2] + sm[3]) * (1.0f / (float)D_DIM);
  const float r = rsqrtf(ms + 1.1920929e-7f);  // eps = finfo(f32).eps
  ushort4* hr = (ushort4*)(h + (size_t)row * D_DIM);
#pragma unroll
  for (int i = 0; i < 4; ++i) {
    float z0 = v[i].x * r, z1 = v[i].y * r, z2 = v[i].z * r, z3 = v[i].w * r;
    ushort4 o;
    o.x = f2bf(z0 / (1.f + __expf(-z0)));
    o.y = f2bf(z1 / (1.f + __expf(-z1)));
    o.z = f2bf(z2 / (1.f + __expf(-z2)));
    o.w = f2bf(z3 / (1.f + __expf(-z3)));
    hr[threadIdx.x + i * 256] = o;
  }
}

__global__ void rms_silu_bf16_k(const u16* __restrict__ x, u16* __restrict__ h) {
  const int row = blockIdx.x;
  const ushort4* xr = (const ushort4*)(x + (size_t)row * D_DIM);
  float4 v[4];
  float ss = 0.f;
#pragma unroll
  for (int i = 0; i < 4; ++i) {
    ushort4 b = xr[threadIdx.x + i * 256];
    v[i] = make_float4(bf2f(b.x), bf2f(b.y), bf2f(b.z), bf2f(b.w));
    ss += v[i].x * v[i].x + v[i].y * v[i].y + v[i].z * v[i].z + v[i].w * v[i].w;
  }
#pragma unroll
  for (int o = 32; o > 0; o >>= 1) ss += __shfl_down(ss, o, 64);
  __shared__ float sm[4];
  if ((threadIdx.x & 63) == 0) sm[threadIdx.x >> 6] = ss;
  __syncthreads();
  const float ms = (sm[0] + sm[1] + sm[2] + sm[3]) * (1.0f / (float)D_DIM);
  const float r = rsqrtf(ms + 1.1920929e-7f);
  ushort4* hr = (ushort4*)(h + (size_t)row * D_DIM);
#pragma unroll
  for (int i = 0; i < 4; ++i) {
    float z0 = v[i].x * r, z1 = v[i].y * r, z2 = v[i].z * r, z3 = v[i].w * r;
    ushort4 o;
    o.x = f2bf(z0 / (1.f + __expf(-z0)));
    o.y = f2bf(z1 / (1.f + __expf(-z1)));
    o.z = f2bf(z2 / (1.f + __expf(-z2)));
    o.w = f2bf(z3 / (1.f + __expf(-z3)));
    hr[threadIdx.x + i * 256] = o;
  }
}

// ---------------- bf16 GEMM: C[M][N] = A[M][K] * B[N][K]^T ----------------
// 256x256 tile, 8 waves (2Mx4N), per-wave C = 128x64 (8x4 frags of 16x16).
// K pipelined in BK=32 slices through a ring of 4 LDS buffers, DEPTH 3:
//   iter s: issue global_load_lds for slice s+3 -> ds_read slice s -> 32 MFMA
//           -> s_waitcnt vmcnt(8); s_barrier      (counted vmcnt, never 0)
// vmcnt(8) leaves slices s+2,s+3 (8 loads/thread) in flight; the oldest 4
// (slice s+1) are complete -> after the barrier slice s+1 is ready wg-wide.
// WAR: STAGE(s+3) writes ring[(s-1)&3], whose ds_reads finished before iter
// s-1's MFMAs (hw lgkmcnt) and barrier -> safe.  Latency budget = 3 iters
// (~900 cyc) >= worst-case HBM miss.
// LDS swizzle (conflict-free at 8-lane b128 phase granularity):
//   read slot g = fq ^ ((fr>>1)&3)  -> any 8 consecutive lanes cover all 32
//   banks (round-2's (fr>>2) key was 2-way conflicted, 2.5e7 cycles).
// Staging pre-swizzles the per-lane GLOBAL source (global_load_lds dest must
// stay linear): sg = (lane&3) ^ ((lane>>3)&3) -- the same involution.
// All row bases (wm, wn, wave*16, +128, +16*mi) are ==0 mod 8, so the
// (row>>1)&3 key is consistent between store and read sides.
template <typename OUT>
__global__ __launch_bounds__(512, 2) void gemm_bt_k(
    const u16* __restrict__ A, const u16* __restrict__ B, OUT* __restrict__ C,
    int M, int N, int K) {
  __shared__ u16 As[4][SLICE_U16];  // 64 KB
  __shared__ u16 Bs[4][SLICE_U16];  // 64 KB

  const int tid = threadIdx.x;
  const int wave = tid >> 6;
  const int lane = tid & 63;

  // XCD-aware bijective swizzle (nwg % 8 == 0): each XCD gets a contiguous
  // chunk of 64 lids = 2 full B-panels (4 MB -> L2-resident per XCD).
  const int nwg = gridDim.x;
  const int cpx = nwg >> 3;
  const int bid = blockIdx.x;
  const int lid = (bid & 7) * cpx + (bid >> 3);
  const int tilesM = M >> 8;
  const int tm = lid % tilesM;
  const int tn = lid / tilesM;
  const int bm = tm * BM;
  const int bn = tn * BN;

  const int wr = wave >> 2;  // 0..1  (M)
  const int wc = wave & 3;   // 0..3  (N)
  const int wm = wr * 128;
  const int wn = wc * 64;

  // ---- fragment LDS read offsets (u16 units), swizzled granule ----
  const int fr = lane & 15;
  const int fq = lane >> 4;
  const int g = fq ^ ((fr >> 1) & 3);
  const int aoff = (wm + fr) * BKS + g * 8;
  const int boff = (wn + fr) * BKS + g * 8;

  // ---- staging: per wave 16 rows x 64B, 2 rounds (rows +0 / +128) each ----
  const int srow = lane >> 2;                      // row within wave's 16
  const int sg = (lane & 3) ^ ((lane >> 3) & 3);   // pre-swizzled src granule
  const size_t ldK = (size_t)K;
  const u16* agp = A + (size_t)(bm + wave * 16 + srow) * ldK + (size_t)(sg * 8);
  const u16* bgp = B + (size_t)(bn + wave * 16 + srow) * ldK + (size_t)(sg * 8);
  const int sdst = wave * 16 * BKS;  // wave-uniform LDS dest (u16)

  f32x4 acc[8][4];
#pragma unroll
  for (int i = 0; i < 8; ++i)
#pragma unroll
    for (int j = 0; j < 4; ++j) acc[i][j] = {0.f, 0.f, 0.f, 0.f};

#define STAGE(s, r)                                                            \
  do {                                                                         \
    const u16* a0 = agp + (size_t)(s)*BKS;                                     \
    const u16* b0 = bgp + (size_t)(s)*BKS;                                     \
    LOAD_LDS16(a0, &As[r][sdst]);                                              \
    LOAD_LDS16(a0 + (size_t)128 * ldK, &As[r][sdst + 128 * BKS]);              \
    LOAD_LDS16(b0, &Bs[r][sdst]);                                              \
    LOAD_LDS16(b0 + (size_t)128 * ldK, &Bs[r][sdst + 128 * BKS]);              \
  } while (0)

// B frags held live (16 VGPR); A frags streamed one at a time (4 VGPR):
// 1 ds_read_b128 -> 4 MFMA, minimal register load (no spill: vmcnt stays
// exact; VGPR_Count 112 + 128 AGPR measured round 2).
#define COMPUTE(r)                                                             \
  do {                                                                         \
    const u16* ab = &As[r][aoff];                                              \
    const u16* bb = &Bs[r][boff];                                              \
    bf16x8 bfv[4];                                                             \
    _Pragma("unroll") for (int ni = 0; ni < 4; ++ni) bfv[ni] =                 \
        __builtin_bit_cast(bf16x8, *(const short8*)(bb + ni * (16 * BKS)));    \
    __builtin_amdgcn_s_setprio(1);                                             \
    _Pragma("unroll") for (int mi = 0; mi < 8; ++mi) {                         \
      bf16x8 af =                                                              \
          __builtin_bit_cast(bf16x8, *(const short8*)(ab + mi * (16 * BKS))); \
      _Pragma("unroll") for (int ni = 0; ni < 4; ++ni) acc[mi][ni] =           \
          __builtin_amdgcn_mfma_f32_16x16x32_bf16(af, bfv[ni],                 \
                                                  acc[mi][ni], 0, 0, 0);       \
    }                                                                          \
    __builtin_amdgcn_s_setprio(0);                                             \
  } while (0)

  const int ns = K / BKS;  // 128
  STAGE(0, 0);
  STAGE(1, 1);
  STAGE(2, 2);
  asm volatile("s_waitcnt vmcnt(8)\n\ts_barrier" ::: "memory");  // slice 0 in
  for (int s = 0; s < ns - 3; ++s) {
    STAGE(s + 3, (s + 3) & 3);
    COMPUTE(s & 3);
    asm volatile("s_waitcnt vmcnt(8)\n\ts_barrier" ::: "memory");
  }
  COMPUTE((ns - 3) & 3);
  asm volatile("s_waitcnt vmcnt(4)\n\ts_barrier" ::: "memory");
  COMPUTE((ns - 2) & 3);
  asm volatile("s_waitcnt vmcnt(0)\n\ts_barrier" ::: "memory");
  COMPUTE((ns - 1) & 3);
#undef STAGE
#undef COMPUTE

  // epilogue: C/D layout col=lane&15, row=(lane>>4)*4+reg (m89-verified)
  const int crow0 = bm + wm + (lane >> 4) * 4;
  const int ccol0 = bn + wn + (lane & 15);
#pragma unroll
  for (int mi = 0; mi < 8; ++mi)
#pragma unroll
    for (int ni = 0; ni < 4; ++ni)
#pragma unroll
      for (int r = 0; r < 4; ++r) {
        float v = acc[mi][ni][r];
        size_t idx = (size_t)(crow0 + mi * 16 + r) * N + (ccol0 + ni * 16);
        if constexpr (__is_same(OUT, float))
          C[idx] = v;
        else
          C[idx] = f2bf(v);
      }
}

// ---------------- driver ----------------
extern "C" void kernel_launch(void* const* d_in, const int* in_sizes, int n_in,
                              void* d_out, int out_size, void* d_ws, size_t ws_size,
                              hipStream_t stream) {
  const float* x = (const float*)d_in[0];
  const float* w[3] = {(const float*)d_in[1], (const float*)d_in[2], (const float*)d_in[3]};

  // ws layout (~160 MB): scale | partials | ternary bf16 (reused) | h bf16 | xmid bf16
  char* ws = (char*)d_ws;
  float* scale = (float*)ws;                               // 16 B
  float* partial = (float*)(ws + 256);                     // 4 KB
  u16* tW = (u16*)(ws + 8192);                             // 32 MB
  u16* h = (u16*)(ws + 8192 + 33554432);                   // 64 MB
  u16* xmid = (u16*)(ws + 8192 + 33554432 + 67108864);     // 64 MB

  dim3 grid((M_TOK / BM) * (D_DIM / BN));  // 512 wgs, 1D for XCD swizzle
  for (int l = 0; l < 3; ++l) {
    abs_partial_k<<<1024, 256, 0, stream>>>(w[l], partial);
    finalize_scale_k<<<1, 256, 0, stream>>>(partial, scale);
    ternarize_k<<<(D_DIM * D_DIM) / 4 / 256, 256, 0, stream>>>(w[l], tW, scale);
    if (l == 0)
      rms_silu_f32_k<<<M_TOK, 256, 0, stream>>>(x, h);
    else
      rms_silu_bf16_k<<<M_TOK, 256, 0, stream>>>(xmid, h);
    if (l == 2)
      gemm_bt_k<float><<<grid, 512, 0, stream>>>(h, tW, (float*)d_out, M_TOK, D_DIM, D_DIM);
    else
      gemm_bt_k<u16><<<grid, 512, 0, stream>>>(h, tW, xmid, M_TOK, D_DIM, D_DIM);
  }
}

// Round 5
// 1156.441 us; speedup vs baseline: 1.2830x; 1.2651x over previous
//
#include <hip/hip_runtime.h>
#include <stdint.h>

typedef unsigned short u16;
typedef __attribute__((ext_vector_type(8))) __bf16 bf16x8;
typedef __attribute__((ext_vector_type(8))) short short8;
typedef __attribute__((ext_vector_type(4))) float f32x4;

#define D_DIM 4096
#define M_TOK 8192

// ---- GEMM geometry: 256x256 tile, 8 waves (2Mx4N), BK=64, 8-phase ----
#define BM 256
#define BN 256
#define BK 64
#define HALF_U16 (128 * 64)  // one half-tile (128 rows x 64 k) = 16 KB

// exact round-to-nearest-even fp32 -> bf16 (inputs finite)
__device__ __forceinline__ u16 f2bf(float f) {
  unsigned u = __builtin_bit_cast(unsigned, f);
  u += 0x7fffu + ((u >> 16) & 1u);
  return (u16)(u >> 16);
}
__device__ __forceinline__ float bf2f(u16 b) {
  unsigned u = ((unsigned)b) << 16;
  return __builtin_bit_cast(float, u);
}

// direct global->LDS DMA, 16B per lane; LDS dest is wave-uniform base + lane*16
#define LOAD_LDS16(gp, lp)                                                     \
  __builtin_amdgcn_global_load_lds(                                            \
      (const __attribute__((address_space(1))) void*)((const void*)(gp)),      \
      (__attribute__((address_space(3))) void*)((void*)(lp)), 16, 0, 0)

// ---------------- abs-mean (two-pass, deterministic) ----------------
__global__ void abs_partial_k(const float* __restrict__ w, float* __restrict__ partial) {
  const int n4 = (D_DIM * D_DIM) / 4;
  float s = 0.f;
  for (int i = blockIdx.x * 256 + threadIdx.x; i < n4; i += 1024 * 256) {
    float4 v = ((const float4*)w)[i];
    s += fabsf(v.x) + fabsf(v.y) + fabsf(v.z) + fabsf(v.w);
  }
#pragma unroll
  for (int o = 32; o > 0; o >>= 1) s += __shfl_down(s, o, 64);
  __shared__ float sm[4];
  if ((threadIdx.x & 63) == 0) sm[threadIdx.x >> 6] = s;
  __syncthreads();
  if (threadIdx.x == 0) partial[blockIdx.x] = sm[0] + sm[1] + sm[2] + sm[3];
}

__global__ void finalize_scale_k(const float* __restrict__ partial, float* __restrict__ scale) {
  float s = 0.f;
  for (int i = threadIdx.x; i < 1024; i += 256) s += partial[i];
#pragma unroll
  for (int o = 32; o > 0; o >>= 1) s += __shfl_down(s, o, 64);
  __shared__ float sm[4];
  if ((threadIdx.x & 63) == 0) sm[threadIdx.x >> 6] = s;
  __syncthreads();
  if (threadIdx.x == 0)
    scale[0] = (sm[0] + sm[1] + sm[2] + sm[3]) * (1.0f / 16777216.0f) + 1e-8f;
}

// ---------------- ternarize: clip(round(w/scale),-1,1) -> bf16 ----------------
__global__ void ternarize_k(const float* __restrict__ w, u16* __restrict__ t,
                            const float* __restrict__ scale) {
  const float sc = scale[0];
  int i = blockIdx.x * 256 + threadIdx.x;  // grid covers n/4 exactly
  float4 v = ((const float4*)w)[i];
  ushort4 o;
  o.x = f2bf(fminf(fmaxf(rintf(v.x / sc), -1.f), 1.f));
  o.y = f2bf(fminf(fmaxf(rintf(v.y / sc), -1.f), 1.f));
  o.z = f2bf(fminf(fmaxf(rintf(v.z / sc), -1.f), 1.f));
  o.w = f2bf(fminf(fmaxf(rintf(v.w / sc), -1.f), 1.f));
  ((ushort4*)t)[i] = o;
}

// ---------------- fused RMSNorm + SiLU -> bf16 ----------------
__global__ void rms_silu_f32_k(const float* __restrict__ x, u16* __restrict__ h) {
  const int row = blockIdx.x;
  const float4* xr = (const float4*)(x + (size_t)row * D_DIM);
  float4 v[4];
  float ss = 0.f;
#pragma unroll
  for (int i = 0; i < 4; ++i) {
    v[i] = xr[threadIdx.x + i * 256];
    ss += v[i].x * v[i].x + v[i].y * v[i].y + v[i].z * v[i].z + v[i].w * v[i].w;
  }
#pragma unroll
  for (int o = 32; o > 0; o >>= 1) ss += __shfl_down(ss, o, 64);
  __shared__ float sm[4];
  if ((threadIdx.x & 63) == 0) sm[threadIdx.x >> 6] = ss;
  __syncthreads();
  const float ms = (sm[0] + sm[1] + sm[2] + sm[3]) * (1.0f / (float)D_DIM);
  const float r = rsqrtf(ms + 1.1920929e-7f);  // eps = finfo(f32).eps
  ushort4* hr = (ushort4*)(h + (size_t)row * D_DIM);
#pragma unroll
  for (int i = 0; i < 4; ++i) {
    float z0 = v[i].x * r, z1 = v[i].y * r, z2 = v[i].z * r, z3 = v[i].w * r;
    ushort4 o;
    o.x = f2bf(z0 / (1.f + __expf(-z0)));
    o.y = f2bf(z1 / (1.f + __expf(-z1)));
    o.z = f2bf(z2 / (1.f + __expf(-z2)));
    o.w = f2bf(z3 / (1.f + __expf(-z3)));
    hr[threadIdx.x + i * 256] = o;
  }
}

__global__ void rms_silu_bf16_k(const u16* __restrict__ x, u16* __restrict__ h) {
  const int row = blockIdx.x;
  const ushort4* xr = (const ushort4*)(x + (size_t)row * D_DIM);
  float4 v[4];
  float ss = 0.f;
#pragma unroll
  for (int i = 0; i < 4; ++i) {
    ushort4 b = xr[threadIdx.x + i * 256];
    v[i] = make_float4(bf2f(b.x), bf2f(b.y), bf2f(b.z), bf2f(b.w));
    ss += v[i].x * v[i].x + v[i].y * v[i].y + v[i].z * v[i].z + v[i].w * v[i].w;
  }
#pragma unroll
  for (int o = 32; o > 0; o >>= 1) ss += __shfl_down(ss, o, 64);
  __shared__ float sm[4];
  if ((threadIdx.x & 63) == 0) sm[threadIdx.x >> 6] = ss;
  __syncthreads();
  const float ms = (sm[0] + sm[1] + sm[2] + sm[3]) * (1.0f / (float)D_DIM);
  const float r = rsqrtf(ms + 1.1920929e-7f);
  ushort4* hr = (ushort4*)(h + (size_t)row * D_DIM);
#pragma unroll
  for (int i = 0; i < 4; ++i) {
    float z0 = v[i].x * r, z1 = v[i].y * r, z2 = v[i].z * r, z3 = v[i].w * r;
    ushort4 o;
    o.x = f2bf(z0 / (1.f + __expf(-z0)));
    o.y = f2bf(z1 / (1.f + __expf(-z1)));
    o.z = f2bf(z2 / (1.f + __expf(-z2)));
    o.w = f2bf(z3 / (1.f + __expf(-z3)));
    hr[threadIdx.x + i * 256] = o;
  }
}

// ---------------- bf16 GEMM: C[M][N] = A[M][K] * B[N][K]^T ----------------
// 8-phase m201-style schedule. 256x256 tile, 8 waves (2Mx4N), per-wave C =
// 128x64 (8mi x 4ni frags). LDS: [2 dbuf][2 halves] x {A,B} of 128x64 u16
// = 128 KiB; dbuf d = t&1.
// Per K-tile t, 4 phases (x2 tiles unrolled = 8 phases/iter), each phase:
//   { ds_reads; stage-issue; s_barrier; s_waitcnt lgkmcnt(0);
//     sched_barrier(0); setprio(1); 16 MFMA; setprio(0); s_barrier }
// The explicit lgkmcnt(0)+sched_barrier(0) after the leading barrier (m201
// discipline, rule #18) guarantees every wave's ds_reads of a buffer are
// COMPLETE before it can reach the barrier after which that buffer is
// re-staged -- closes the WAR window regardless of where hipcc sinks MFMAs.
//   ph0: rd B[kk0](4)+A[kk0,mi0-3](4); stage t+1.Ah0
//   ph1: rd A[kk0,mi4-7](4);           stage t+1.Ah1
//   ph2: rd B[kk1](4)+A[kk1,mi0-3](4)
//   ph3: rd A[kk1,mi4-7](4);           stage t+2.Bh0,Bh1
//        trailing sync = s_waitcnt vmcnt(4); s_barrier  (counted, never 0)
// vmcnt ledger: steady-state outstanding after ph3 = [t+1.B(4), t+1.A(4),
// t+2.B(4)]; vmcnt(4) -> t+1 fully landed wg-wide, t+2.B stays in flight.
// WAR: t+1.A writes AS[d^1], last read tile t-1 ph3 (completed via that
// phase's lgkmcnt(0), barrier-separated).  t+2.B writes BS[d], last read
// this tile ph2 (completed via ph2's lgkmcnt(0), barrier-separated).
// lgkmcnt(0) does NOT touch the staging pipeline: global_load_lds counts
// in vmcnt only (ISA §6/§7), so the deep prefetch survives.
// Swizzle (zero-conflict, bank-enumerated): 8 granules (16B) per 128B row,
// slot = g ^ (row&7); staging pre-swizzles the per-lane global source
// (global_load_lds dest must stay linear): src granule = (lane&7)^(lane>>3).
// All row bases (wr*128, (wc&1)*64, mi*16, ni*16, wave*8, +64, +128) are
// ==0 mod 8, so the (row&7) key is consistent between store and read sides.
#define LD8(p) __builtin_bit_cast(bf16x8, *(const short8*)(p))

template <typename OUT>
__global__ __launch_bounds__(512, 2) void gemm_bt_k(
    const u16* __restrict__ A, const u16* __restrict__ B, OUT* __restrict__ C,
    int M, int N, int K) {
  __shared__ u16 AS[2][2][HALF_U16];  // 64 KB
  __shared__ u16 BS[2][2][HALF_U16];  // 64 KB

  const int tid = threadIdx.x;
  const int wave = tid >> 6;
  const int lane = tid & 63;

  // XCD-aware bijective swizzle (nwg % 8 == 0): 64 consecutive lids per XCD
  // = 2 full B-panels (4 MB -> L2-resident per XCD).
  const int nwg = gridDim.x;
  const int cpx = nwg >> 3;
  const int bid = blockIdx.x;
  const int lid = (bid & 7) * cpx + (bid >> 3);
  const int tilesM = M >> 8;
  const int bm = (lid % tilesM) * BM;
  const int bn = (lid / tilesM) * BN;

  const int wr = wave >> 2;   // 0..1 (M half)
  const int wc = wave & 3;    // 0..3 (N quarter)
  const int wcH = wc >> 1;    // B half
  const int wm = wr * 128;
  const int wn = wc * 64;

  // ---- fragment LDS read offsets (u16 units) ----
  const int fr = lane & 15;
  const int fq = lane >> 4;
  const int key = fr & 7;
  const int ao0 = fr * 64 + ((fq) ^ key) * 8;        // kk=0
  const int ao1 = fr * 64 + ((4 + fq) ^ key) * 8;    // kk=1
  const int bo0 = ((wc & 1) * 64 + fr) * 64 + ((fq) ^ key) * 8;
  const int bo1 = ((wc & 1) * 64 + fr) * 64 + ((4 + fq) ^ key) * 8;

  // ---- staging addressing: wave w covers rows {j*64 + w*8 .. +7} ----
  const int srow8 = lane >> 3;
  const int sgc = ((lane & 7) ^ srow8) * 8;  // pre-swizzled source granule
  const size_t ldK = (size_t)K;
  const u16* aS = A + (size_t)(bm + wave * 8 + srow8) * ldK + sgc;
  const u16* bS = B + (size_t)(bn + wave * 8 + srow8) * ldK + sgc;
  const int sdst = wave * 8 * 64;  // u16; +4096 for j=1

#define STAGE_A(tt, hh, DD)                                                    \
  do {                                                                         \
    const u16* s0 = aS + (size_t)((hh) * 128) * ldK + (size_t)(tt) * 64;       \
    LOAD_LDS16(s0, &AS[DD][hh][sdst]);                                         \
    LOAD_LDS16(s0 + (size_t)64 * ldK, &AS[DD][hh][sdst + 4096]);               \
  } while (0)
#define STAGE_B(tt, hh, DD)                                                    \
  do {                                                                         \
    const u16* s0 = bS + (size_t)((hh) * 128) * ldK + (size_t)(tt) * 64;       \
    LOAD_LDS16(s0, &BS[DD][hh][sdst]);                                         \
    LOAD_LDS16(s0 + (size_t)64 * ldK, &BS[DD][hh][sdst + 4096]);               \
  } while (0)

  f32x4 acc[8][4];
#pragma unroll
  for (int i = 0; i < 8; ++i)
#pragma unroll
    for (int j = 0; j < 4; ++j) acc[i][j] = {0.f, 0.f, 0.f, 0.f};

#define BAR() asm volatile("s_barrier" ::: "memory")
#define LGKM0()                                                                \
  do {                                                                         \
    asm volatile("s_waitcnt lgkmcnt(0)" ::: "memory");                         \
    __builtin_amdgcn_sched_barrier(0);                                         \
  } while (0)
#define MFMA16(MB, BV)                                                         \
  do {                                                                         \
    __builtin_amdgcn_s_setprio(1);                                             \
    _Pragma("unroll") for (int mi = 0; mi < 4; ++mi)                           \
        _Pragma("unroll") for (int ni = 0; ni < 4; ++ni) acc[MB + mi][ni] =    \
            __builtin_amdgcn_mfma_f32_16x16x32_bf16(a[mi], BV[ni],             \
                                                    acc[MB + mi][ni], 0, 0, 0);\
    __builtin_amdgcn_s_setprio(0);                                             \
  } while (0)

#define TILE(D, t, STA, STB, SYNC)                                             \
  do {                                                                         \
    const u16* aRd = &AS[D][wr][0];                                            \
    const u16* bRd = &BS[D][wcH][0];                                           \
    bf16x8 a[4], bv[4];                                                        \
    /* ph0: B kk0 + A kk0 mi0-3 */                                             \
    _Pragma("unroll") for (int ni = 0; ni < 4; ++ni)                           \
        bv[ni] = LD8(bRd + bo0 + ni * 1024);                                   \
    _Pragma("unroll") for (int mi = 0; mi < 4; ++mi)                           \
        a[mi] = LD8(aRd + ao0 + mi * 1024);                                    \
    if (STA) STAGE_A((t) + 1, 0, (D) ^ 1);                                     \
    BAR();                                                                     \
    LGKM0();                                                                   \
    MFMA16(0, bv);                                                             \
    BAR();                                                                     \
    /* ph1: A kk0 mi4-7 (B held) */                                            \
    _Pragma("unroll") for (int mi = 0; mi < 4; ++mi)                           \
        a[mi] = LD8(aRd + ao0 + (mi + 4) * 1024);                              \
    if (STA) STAGE_A((t) + 1, 1, (D) ^ 1);                                     \
    BAR();                                                                     \
    LGKM0();                                                                   \
    MFMA16(4, bv);                                                             \
    BAR();                                                                     \
    /* ph2: B kk1 + A kk1 mi0-3 */                                             \
    _Pragma("unroll") for (int ni = 0; ni < 4; ++ni)                           \
        bv[ni] = LD8(bRd + bo1 + ni * 1024);                                   \
    _Pragma("unroll") for (int mi = 0; mi < 4; ++mi)                           \
        a[mi] = LD8(aRd + ao1 + mi * 1024);                                    \
    BAR();                                                                     \
    LGKM0();                                                                   \
    MFMA16(0, bv);                                                             \
    BAR();                                                                     \
    /* ph3: A kk1 mi4-7 (B held); stage next B; counted trailing sync */       \
    _Pragma("unroll") for (int mi = 0; mi < 4; ++mi)                           \
        a[mi] = LD8(aRd + ao1 + (mi + 4) * 1024);                              \
    if (STB) {                                                                 \
      STAGE_B((t) + 2, 0, (D));                                                \
      STAGE_B((t) + 2, 1, (D));                                                \
    }                                                                          \
    BAR();                                                                     \
    LGKM0();                                                                   \
    MFMA16(4, bv);                                                             \
    SYNC;                                                                      \
  } while (0)

  // ---- prologue: t0 fully + t1.B; then counted wait (t1.B stays in flight)
  STAGE_A(0, 0, 0);
  STAGE_A(0, 1, 0);
  STAGE_B(0, 0, 0);
  STAGE_B(0, 1, 0);
  STAGE_B(1, 0, 1);
  STAGE_B(1, 1, 1);
  asm volatile("s_waitcnt vmcnt(4)\n\ts_barrier" ::: "memory");

  const int nt = K / BK;  // 64
#pragma clang loop unroll(disable)
  for (int t = 0; t < nt - 2; t += 2) {
    TILE(0, t, 1, 1, asm volatile("s_waitcnt vmcnt(4)\n\ts_barrier" ::: "memory"));
    TILE(1, t + 1, 1, 1, asm volatile("s_waitcnt vmcnt(4)\n\ts_barrier" ::: "memory"));
  }
  // tail: tile nt-2 stages (nt-1).A only, drains; tile nt-1 pure compute
  TILE(0, nt - 2, 1, 0, asm volatile("s_waitcnt vmcnt(0)\n\ts_barrier" ::: "memory"));
  TILE(1, nt - 1, 0, 0, (void)0);
#undef TILE
#undef MFMA16
#undef LGKM0
#undef BAR
#undef STAGE_A
#undef STAGE_B

  // epilogue: C/D layout col=lane&15, row=(lane>>4)*4+reg (m89-verified)
  const int crow0 = bm + wm + (lane >> 4) * 4;
  const int ccol0 = bn + wn + (lane & 15);
#pragma unroll
  for (int mi = 0; mi < 8; ++mi)
#pragma unroll
    for (int ni = 0; ni < 4; ++ni)
#pragma unroll
      for (int r = 0; r < 4; ++r) {
        float v = acc[mi][ni][r];
        size_t idx = (size_t)(crow0 + mi * 16 + r) * N + (ccol0 + ni * 16);
        if constexpr (__is_same(OUT, float))
          C[idx] = v;
        else
          C[idx] = f2bf(v);
      }
}

// ---------------- driver ----------------
extern "C" void kernel_launch(void* const* d_in, const int* in_sizes, int n_in,
                              void* d_out, int out_size, void* d_ws, size_t ws_size,
                              hipStream_t stream) {
  const float* x = (const float*)d_in[0];
  const float* w[3] = {(const float*)d_in[1], (const float*)d_in[2], (const float*)d_in[3]};

  // ws layout (~160 MB): scale | partials | ternary bf16 (reused) | h bf16 | xmid bf16
  char* ws = (char*)d_ws;
  float* scale = (float*)ws;                               // 16 B
  float* partial = (float*)(ws + 256);                     // 4 KB
  u16* tW = (u16*)(ws + 8192);                             // 32 MB
  u16* h = (u16*)(ws + 8192 + 33554432);                   // 64 MB
  u16* xmid = (u16*)(ws + 8192 + 33554432 + 67108864);     // 64 MB

  dim3 grid((M_TOK / BM) * (D_DIM / BN));  // 512 wgs, 1D for XCD swizzle
  for (int l = 0; l < 3; ++l) {
    abs_partial_k<<<1024, 256, 0, stream>>>(w[l], partial);
    finalize_scale_k<<<1, 256, 0, stream>>>(partial, scale);
    ternarize_k<<<(D_DIM * D_DIM) / 4 / 256, 256, 0, stream>>>(w[l], tW, scale);
    if (l == 0)
      rms_silu_f32_k<<<M_TOK, 256, 0, stream>>>(x, h);
    else
      rms_silu_bf16_k<<<M_TOK, 256, 0, stream>>>(xmid, h);
    if (l == 2)
      gemm_bt_k<float><<<grid, 512, 0, stream>>>(h, tW, (float*)d_out, M_TOK, D_DIM, D_DIM);
    else
      gemm_bt_k<u16><<<grid, 512, 0, stream>>>(h, tW, xmid, M_TOK, D_DIM, D_DIM);
  }
}